// Round 1
// baseline (1628.952 us; speedup 1.0000x reference)
//
#include <hip/hip_runtime.h>
#include <math.h>

// Fused: MLP(128->256->256->9) + (out+I)@rot + polar projection (scaled Newton)
// Round 1: pure fp32 correctness anchor. VALU-bound by design (~330us roofline).

#define N_ROWS   262144
#define FEAT     128
#define HID      256
#define TM       32          // rows per block
#define KC       16          // k-chunk staged in LDS
#define NTHREADS 128         // 4 ty-groups x 32 tx; micro-tile 8 rows x 8 cols

// LDS layout (bytes). H2 overlays As+Ws (region1) after layer-2 compute.
#define LDH2        (HID + 4)                   // 260: pads layer-3 reads across rows onto distinct banks
#define SZ_REGION1  (TM * LDH2 * 4)             // 33280 >= As(16384)+Ws(16384)
#define OFF_WS      16384
#define OFF_H1      SZ_REGION1                  // 33280, stride HID (reads are broadcasts)
#define OFF_W3      (OFF_H1 + TM*HID*4)         // 66048
#define OFF_B1      (OFF_W3 + HID*9*4)          // 75264
#define OFF_B2      (OFF_B1 + HID*4)            // 76288
#define OFF_B3      (OFF_B2 + HID*4)            // 77312
#define OFF_RS      (OFF_B3 + 48)               // 77360, [TM][12]
#define OFF_MS      (OFF_RS + TM*12*4)          // 78896, [TM][12]
#define SMEM_SZ     (OFF_MS + TM*12*4)          // 80432 B -> 2 blocks/CU (160 KiB LDS)

__device__ __forceinline__ void gemm_relu_layer(
    const float* __restrict__ Asrc, int lda, int K,
    const float* __restrict__ Wglob, const float* __restrict__ bias_s,
    float* __restrict__ Ws, float* __restrict__ Hdst, int ldh,
    int ty, int tx, int tid)
{
    float acc[8][8];
#pragma unroll
    for (int i = 0; i < 8; ++i)
#pragma unroll
        for (int j = 0; j < 8; ++j) acc[i][j] = 0.0f;

    for (int kc = 0; kc < K; kc += KC) {
        __syncthreads();   // previous chunk fully consumed before overwrite
        {
            const float4* src = (const float4*)(Wglob + (size_t)kc * HID);
            float4* dst = (float4*)Ws;
            for (int t = tid; t < KC * HID / 4; t += NTHREADS) dst[t] = src[t];
        }
        __syncthreads();
#pragma unroll
        for (int kk4 = 0; kk4 < KC; kk4 += 4) {
            float4 a4[8];
#pragma unroll
            for (int i = 0; i < 8; ++i)
                a4[i] = *(const float4*)(Asrc + (ty * 8 + i) * lda + kc + kk4);
#pragma unroll
            for (int q = 0; q < 4; ++q) {
                const float4 b0 = *(const float4*)(&Ws[(kk4 + q) * HID + tx * 8]);
                const float4 b1v = *(const float4*)(&Ws[(kk4 + q) * HID + tx * 8 + 4]);
                const float bb[8] = {b0.x, b0.y, b0.z, b0.w, b1v.x, b1v.y, b1v.z, b1v.w};
#pragma unroll
                for (int i = 0; i < 8; ++i) {
                    const float av = (q == 0) ? a4[i].x : (q == 1) ? a4[i].y
                                    : (q == 2) ? a4[i].z : a4[i].w;
#pragma unroll
                    for (int j = 0; j < 8; ++j) acc[i][j] += av * bb[j];
                }
            }
        }
    }
    __syncthreads();   // all compute done before Hdst may overlay Ws/As
#pragma unroll
    for (int i = 0; i < 8; ++i) {
        const int r = ty * 8 + i;
        float4 v0, v1;
        v0.x = fmaxf(acc[i][0] + bias_s[tx * 8 + 0], 0.0f);
        v0.y = fmaxf(acc[i][1] + bias_s[tx * 8 + 1], 0.0f);
        v0.z = fmaxf(acc[i][2] + bias_s[tx * 8 + 2], 0.0f);
        v0.w = fmaxf(acc[i][3] + bias_s[tx * 8 + 3], 0.0f);
        v1.x = fmaxf(acc[i][4] + bias_s[tx * 8 + 4], 0.0f);
        v1.y = fmaxf(acc[i][5] + bias_s[tx * 8 + 5], 0.0f);
        v1.z = fmaxf(acc[i][6] + bias_s[tx * 8 + 6], 0.0f);
        v1.w = fmaxf(acc[i][7] + bias_s[tx * 8 + 7], 0.0f);
        *(float4*)(Hdst + r * ldh + tx * 8) = v0;
        *(float4*)(Hdst + r * ldh + tx * 8 + 4) = v1;
    }
    __syncthreads();
}

__global__ __launch_bounds__(NTHREADS)
void fused_rotmlp_polar(const float* __restrict__ rot,
                        const float* __restrict__ feat,
                        const float* __restrict__ W1, const float* __restrict__ b1,
                        const float* __restrict__ W2, const float* __restrict__ b2,
                        const float* __restrict__ W3, const float* __restrict__ b3,
                        float* __restrict__ out)
{
    __shared__ __align__(16) unsigned char smem[SMEM_SZ];
    float* As  = (float*)(smem);             // [TM][FEAT]
    float* Ws  = (float*)(smem + OFF_WS);    // [KC][HID]
    float* H2  = (float*)(smem);             // [TM][LDH2] overlays As+Ws
    float* H1  = (float*)(smem + OFF_H1);    // [TM][HID]
    float* W3s = (float*)(smem + OFF_W3);    // [HID][9]
    float* b1s = (float*)(smem + OFF_B1);
    float* b2s = (float*)(smem + OFF_B2);
    float* b3s = (float*)(smem + OFF_B3);
    float* Rs  = (float*)(smem + OFF_RS);    // [TM][12]
    float* Ms  = (float*)(smem + OFF_MS);    // [TM][12]

    const int tid  = threadIdx.x;
    const int ty   = tid >> 5;               // 0..3
    const int tx   = tid & 31;               // 0..31
    const int row0 = blockIdx.x * TM;

    // ---- stage feature tile + small params + rotation ----
    {
        const float4* src = (const float4*)(feat + (size_t)row0 * FEAT);
        float4* dst = (float4*)As;
        for (int t = tid; t < TM * FEAT / 4; t += NTHREADS) dst[t] = src[t];
        const float4* w3v = (const float4*)W3;
        float4* w3d = (float4*)W3s;
        for (int t = tid; t < HID * 9 / 4; t += NTHREADS) w3d[t] = w3v[t];
        const float4* b1v = (const float4*)b1; float4* b1d = (float4*)b1s;
        for (int t = tid; t < HID / 4; t += NTHREADS) b1d[t] = b1v[t];
        const float4* b2v = (const float4*)b2; float4* b2d = (float4*)b2s;
        for (int t = tid; t < HID / 4; t += NTHREADS) b2d[t] = b2v[t];
        if (tid < 9) b3s[tid] = b3[tid];
        for (int t = tid; t < TM * 9; t += NTHREADS)
            Rs[(t / 9) * 12 + (t % 9)] = rot[(size_t)row0 * 9 + t];
    }
    // (first __syncthreads happens inside gemm_relu_layer before compute)

    // ---- layer 1: H1 = relu(As @ W1 + b1) ----
    gemm_relu_layer(As, FEAT, FEAT, W1, b1s, Ws, H1, HID, ty, tx, tid);
    // ---- layer 2: H2 = relu(H1 @ W2 + b2) (H2 overlays As/Ws) ----
    gemm_relu_layer(H1, HID, HID, W2, b2s, Ws, H2, LDH2, ty, tx, tid);

    // ---- layer 3: Ms[r][o] = b3[o] + sum_c H2[r][c]*W3[c][o] ----
    for (int t = tid; t < TM * 9; t += NTHREADS) {
        const int r = t / 9, o = t - 9 * r;
        float s = b3s[o];
#pragma unroll 16
        for (int c4 = 0; c4 < HID / 4; ++c4) {
            const float4 h = *(const float4*)(&H2[r * LDH2 + c4 * 4]);
            s += h.x * W3s[(c4 * 4 + 0) * 9 + o];
            s += h.y * W3s[(c4 * 4 + 1) * 9 + o];
            s += h.z * W3s[(c4 * 4 + 2) * 9 + o];
            s += h.w * W3s[(c4 * 4 + 3) * 9 + o];
        }
        Ms[r * 12 + o] = s;
    }
    __syncthreads();

    // ---- per-row: X = (M+I)@R, then polar factor via scaled Newton ----
    if (tid < TM) {
        const int r = tid;
        const float m0 = Ms[r*12+0] + 1.0f, m1 = Ms[r*12+1],        m2 = Ms[r*12+2];
        const float m3 = Ms[r*12+3],        m4 = Ms[r*12+4] + 1.0f, m5 = Ms[r*12+5];
        const float m6 = Ms[r*12+6],        m7 = Ms[r*12+7],        m8 = Ms[r*12+8] + 1.0f;
        const float r0 = Rs[r*12+0], r1 = Rs[r*12+1], r2 = Rs[r*12+2];
        const float r3 = Rs[r*12+3], r4 = Rs[r*12+4], r5 = Rs[r*12+5];
        const float r6 = Rs[r*12+6], r7 = Rs[r*12+7], r8 = Rs[r*12+8];

        float x0 = m0*r0 + m1*r3 + m2*r6;
        float x1 = m0*r1 + m1*r4 + m2*r7;
        float x2 = m0*r2 + m1*r5 + m2*r8;
        float x3 = m3*r0 + m4*r3 + m5*r6;
        float x4 = m3*r1 + m4*r4 + m5*r7;
        float x5 = m3*r2 + m4*r5 + m5*r8;
        float x6 = m6*r0 + m7*r3 + m8*r6;
        float x7 = m6*r1 + m7*r4 + m8*r7;
        float x8 = m6*r2 + m7*r5 + m8*r8;

        // scaled Newton: X <- 0.5*(mu*X + cof(X)/(mu*det)); converges to U@Vh
#pragma unroll 1
        for (int it = 0; it < 16; ++it) {
            const float c0 = x4*x8 - x5*x7;
            const float c1 = x5*x6 - x3*x8;
            const float c2 = x3*x7 - x4*x6;
            const float c3 = x2*x7 - x1*x8;
            const float c4 = x0*x8 - x2*x6;
            const float c5 = x1*x6 - x0*x7;
            const float c6 = x1*x5 - x2*x4;
            const float c7 = x2*x3 - x0*x5;
            const float c8 = x0*x4 - x1*x3;
            const float det = x0*c0 + x1*c1 + x2*c2;
            const float ad  = fmaxf(fabsf(det), 1e-30f);
            const float mu  = 1.0f / cbrtf(ad);              // |det|^(-1/3)
            const float dsafe = copysignf(ad, det);
            const float s1 = 0.5f * mu;
            const float s2 = 0.5f / (mu * dsafe);
            x0 = s1*x0 + s2*c0;  x1 = s1*x1 + s2*c1;  x2 = s1*x2 + s2*c2;
            x3 = s1*x3 + s2*c3;  x4 = s1*x4 + s2*c4;  x5 = s1*x5 + s2*c5;
            x6 = s1*x6 + s2*c6;  x7 = s1*x7 + s2*c7;  x8 = s1*x8 + s2*c8;
        }
        Ms[r*12+0] = x0; Ms[r*12+1] = x1; Ms[r*12+2] = x2;
        Ms[r*12+3] = x3; Ms[r*12+4] = x4; Ms[r*12+5] = x5;
        Ms[r*12+6] = x6; Ms[r*12+7] = x7; Ms[r*12+8] = x8;
    }
    __syncthreads();

    // ---- coalesced output: out (N*9) then logdet zeros (N) ----
    for (int t = tid; t < TM * 9; t += NTHREADS)
        out[(size_t)row0 * 9 + t] = Ms[(t / 9) * 12 + (t % 9)];
    for (int t = tid; t < TM; t += NTHREADS)
        out[(size_t)N_ROWS * 9 + row0 + t] = 0.0f;
}

extern "C" void kernel_launch(void* const* d_in, const int* in_sizes, int n_in,
                              void* d_out, int out_size, void* d_ws, size_t ws_size,
                              hipStream_t stream) {
    const float* rot  = (const float*)d_in[0];
    const float* feat = (const float*)d_in[1];
    const float* W1   = (const float*)d_in[2];
    const float* b1   = (const float*)d_in[3];
    const float* W2   = (const float*)d_in[4];
    const float* b2   = (const float*)d_in[5];
    const float* W3   = (const float*)d_in[6];
    const float* b3   = (const float*)d_in[7];
    float* out = (float*)d_out;
    (void)in_sizes; (void)n_in; (void)out_size; (void)d_ws; (void)ws_size;

    dim3 grid(N_ROWS / TM), block(NTHREADS);
    hipLaunchKernelGGL(fused_rotmlp_polar, grid, block, 0, stream,
                       rot, feat, W1, b1, W2, b2, W3, b3, out);
}

// Round 3
// 423.764 us; speedup vs baseline: 3.8440x; 3.8440x over previous
//
#include <hip/hip_runtime.h>
#include <math.h>

// Round 3: split-FP16 MFMA (hi/lo, 3 passes -> ~fp32 accuracy) for layers 1-2,
// lane-parallel fp32 layer-3, verified Newton-polar tail.
// LDS overlays -> 81 KB -> 2 blocks/CU.

#define N_ROWS 262144
#define FEAT   128
#define HID    256
#define TM     64
#define NT     256
#define NBLK   (N_ROWS/TM)

typedef _Float16 h8v __attribute__((ext_vector_type(8)));   // 8 x fp16 (4 VGPRs)
typedef float    f4v __attribute__((ext_vector_type(4)));   // MFMA accumulator

// d_ws: W1/W2 fp16 hi/lo in MFMA-fragment order (393216 B total)
#define WS_W1H 0
#define WS_W1L 65536
#define WS_W2H 131072
#define WS_W2L 262144

// LDS (bytes). Timeline overlays:
//   phase1: A hi/lo [0,32768) ; phase2: H1 hi/lo [0,65536) ; phase3: H2 f32 [0,65536)
#define OFF_AH  0
#define OFF_AL  16384
#define OFF_H1H 0
#define OFF_H1L 32768
#define W3SEC   2320                      // [4 sections][64 rows][9] f32, +16B section skew
#define OFF_W3  65536
#define OFF_B3  (OFF_W3 + 4*W3SEC)        // 74816
#define OFF_RS  (OFF_B3 + 64)             // 74880  [64][12] f32
#define OFF_MS  (OFF_RS + TM*12*4)        // 77952  [64][12] f32
#define SMEM_SZ (OFF_MS + TM*12*4)        // 81024 B -> 2 blocks/CU

__device__ __forceinline__ unsigned short hbits(_Float16 h) {
    return __builtin_bit_cast(unsigned short, h);
}

// ---- prep: pack W1,W2 to fp16 hi/lo in fragment order ----
// fragment elem e = (((ks*16+cb)*64)+lane)*8 + j  <->  W[k][n],
// k = ks*32 + (lane>>4)*8 + j, n = cb*16 + (lane&15).  (same k-labeling as A reads)
__global__ __launch_bounds__(256)
void prep_weights(const float* __restrict__ W1, const float* __restrict__ W2,
                  unsigned char* __restrict__ ws) {
    int e = blockIdx.x * 256 + threadIdx.x;
    unsigned short* w1h = (unsigned short*)(ws + WS_W1H);
    unsigned short* w1l = (unsigned short*)(ws + WS_W1L);
    unsigned short* w2h = (unsigned short*)(ws + WS_W2H);
    unsigned short* w2l = (unsigned short*)(ws + WS_W2L);
    if (e < FEAT * HID) {
        int j = e & 7, lane = (e >> 3) & 63, cb = (e >> 9) & 15, ks = e >> 13;
        int k = ks * 32 + ((lane >> 4) << 3) + j, n = cb * 16 + (lane & 15);
        float v = W1[k * HID + n];
        _Float16 h = (_Float16)v, l = (_Float16)(v - (float)h);
        w1h[e] = hbits(h); w1l[e] = hbits(l);
    } else if (e < FEAT * HID + HID * HID) {
        int e2 = e - FEAT * HID;
        int j = e2 & 7, lane = (e2 >> 3) & 63, cb = (e2 >> 9) & 15, ks = e2 >> 13;
        int k = ks * 32 + ((lane >> 4) << 3) + j, n = cb * 16 + (lane & 15);
        float v = W2[k * HID + n];
        _Float16 h = (_Float16)v, l = (_Float16)(v - (float)h);
        w2h[e2] = hbits(h); w2l[e2] = hbits(l);
    }
}

// ---- split-fp16 MFMA layer: acc += A @ B over K = KSTEPS*32 (3 passes) ----
template<int KSTEPS, int ROWSTRIDE>
__device__ __forceinline__ void mfma_layer(const unsigned char* AH, const unsigned char* AL,
                                           const h8v* __restrict__ BH, const h8v* __restrict__ BL,
                                           f4v acc[4][4], int lane, int qc) {
#pragma unroll 2
    for (int ks = 0; ks < KSTEPS; ++ks) {
        h8v ah[4], al[4];
#pragma unroll
        for (int rt = 0; rt < 4; ++rt) {
            int row = rt * 16 + (lane & 15);
            unsigned byt = (unsigned)(row * ROWSTRIDE + ks * 64 + ((lane >> 4) << 4));
            byt ^= (unsigned)((row & 7) << 4);          // bank swizzle (2-way max)
            ah[rt] = *(const h8v*)(AH + byt);
            al[rt] = *(const h8v*)(AL + byt);
        }
#pragma unroll
        for (int ct = 0; ct < 4; ++ct) {
            int fi = ((ks * 16 + qc * 4 + ct) << 6) + lane;
            h8v bh = BH[fi], bl = BL[fi];
#pragma unroll
            for (int rt = 0; rt < 4; ++rt) {
                acc[rt][ct] = __builtin_amdgcn_mfma_f32_16x16x32_f16(ah[rt], bh, acc[rt][ct], 0, 0, 0);
                acc[rt][ct] = __builtin_amdgcn_mfma_f32_16x16x32_f16(ah[rt], bl, acc[rt][ct], 0, 0, 0);
                acc[rt][ct] = __builtin_amdgcn_mfma_f32_16x16x32_f16(al[rt], bh, acc[rt][ct], 0, 0, 0);
            }
        }
    }
}

__global__ __launch_bounds__(NT, 2)
void fused_main(const float* __restrict__ rot, const float* __restrict__ feat,
                const float* __restrict__ b1, const float* __restrict__ b2,
                const float* __restrict__ W3, const float* __restrict__ b3,
                const unsigned char* __restrict__ ws, float* __restrict__ out) {
    __shared__ __align__(16) unsigned char smem[SMEM_SZ];
    const int tid = threadIdx.x, lane = tid & 63, w = tid >> 6;
    const int row0 = blockIdx.x * TM;

    // ---- stage: feature -> A hi/lo (swizzled), W3 (bank-sectioned), b3, rotation ----
    {
        const float4* f4 = (const float4*)(feat + (size_t)row0 * FEAT);
        for (int t = tid; t < TM * FEAT / 4; t += NT) {
            float4 v = f4[t];
            int row = t >> 5, c4 = t & 31;
            unsigned byt = (unsigned)(row * 256 + c4 * 8) ^ (unsigned)((row & 7) << 4);
            _Float16 h0 = (_Float16)v.x, h1v = (_Float16)v.y, h2v = (_Float16)v.z, h3v = (_Float16)v.w;
            _Float16 l0 = (_Float16)(v.x - (float)h0), l1v = (_Float16)(v.y - (float)h1v);
            _Float16 l2v = (_Float16)(v.z - (float)h2v), l3v = (_Float16)(v.w - (float)h3v);
            uint2 hp, lp;
            hp.x = (unsigned)hbits(h0)  | ((unsigned)hbits(h1v) << 16);
            hp.y = (unsigned)hbits(h2v) | ((unsigned)hbits(h3v) << 16);
            lp.x = (unsigned)hbits(l0)  | ((unsigned)hbits(l1v) << 16);
            lp.y = (unsigned)hbits(l2v) | ((unsigned)hbits(l3v) << 16);
            *(uint2*)(smem + OFF_AH + byt) = hp;
            *(uint2*)(smem + OFF_AL + byt) = lp;
        }
        for (int t = tid; t < HID * 9; t += NT) {      // W3 sectioned: kills 64-row-stride conflicts
            int c = t / 9, o = t - 9 * c;
            *(float*)(smem + OFF_W3 + (c >> 6) * W3SEC + (c & 63) * 36 + o * 4) = W3[t];
        }
        if (tid < 9) ((float*)(smem + OFF_B3))[tid] = b3[tid];
        float* Rs = (float*)(smem + OFF_RS);
        for (int t = tid; t < TM * 9; t += NT)
            Rs[(t / 9) * 12 + (t % 9)] = rot[(size_t)row0 * 9 + t];
    }
    __syncthreads();

    // ---- layer 1: H1 = relu(A @ W1 + b1), split-fp16 ----
    f4v acc[4][4];
#pragma unroll
    for (int i = 0; i < 4; ++i)
#pragma unroll
        for (int j = 0; j < 4; ++j) acc[i][j] = (f4v)0.0f;
    mfma_layer<4, 256>(smem + OFF_AH, smem + OFF_AL,
                       (const h8v*)(ws + WS_W1H), (const h8v*)(ws + WS_W1L), acc, lane, w);
    __syncthreads();          // A fully consumed by ALL waves before H1 overlays it
#pragma unroll
    for (int ct = 0; ct < 4; ++ct) {
        int col = (w * 4 + ct) * 16 + (lane & 15);
        float bias = b1[col];
#pragma unroll
        for (int rt = 0; rt < 4; ++rt)
#pragma unroll
            for (int r = 0; r < 4; ++r) {
                int row = rt * 16 + ((lane >> 4) << 2) + r;   // C/D: col=lane&15, row=(lane>>4)*4+reg
                float v = fmaxf(acc[rt][ct][r] + bias, 0.0f);
                _Float16 h = (_Float16)v, l = (_Float16)(v - (float)h);
                unsigned byt = (unsigned)(row * 512 + col * 2) ^ (unsigned)((row & 7) << 4);
                *(unsigned short*)(smem + OFF_H1H + byt) = hbits(h);
                *(unsigned short*)(smem + OFF_H1L + byt) = hbits(l);
            }
    }
    __syncthreads();

    // ---- layer 2: H2 = relu(H1 @ W2 + b2), split-fp16 ----
#pragma unroll
    for (int i = 0; i < 4; ++i)
#pragma unroll
        for (int j = 0; j < 4; ++j) acc[i][j] = (f4v)0.0f;
    mfma_layer<8, 512>(smem + OFF_H1H, smem + OFF_H1L,
                       (const h8v*)(ws + WS_W2H), (const h8v*)(ws + WS_W2L), acc, lane, w);
    __syncthreads();          // H1 fully consumed before H2 overlays it
#pragma unroll
    for (int ct = 0; ct < 4; ++ct) {
        int col = (w * 4 + ct) * 16 + (lane & 15);
        float bias = b2[col];
#pragma unroll
        for (int rt = 0; rt < 4; ++rt)
#pragma unroll
            for (int r = 0; r < 4; ++r) {
                int row = rt * 16 + ((lane >> 4) << 2) + r;
                unsigned byt = (unsigned)(row * 1024 + col * 4) ^ (unsigned)((row & 7) << 4);
                *(float*)(smem + byt) = fmaxf(acc[rt][ct][r] + bias, 0.0f);   // H2 f32, swizzled
            }
    }
    __syncthreads();

    // ---- layer 3 (fp32): lane (r, kg) holds 9 partials over its 64-col quarter ----
    const int r3 = (w << 4) + (lane & 15), kg = lane >> 4;
    float p[9];
#pragma unroll
    for (int o = 0; o < 9; ++o) p[o] = 0.0f;
#pragma unroll 4
    for (int j = 0; j < 16; ++j) {
        int col = kg * 64 + j * 4;
        unsigned byt = (unsigned)(r3 * 1024 + col * 4) ^ (unsigned)((r3 & 7) << 4);
        float4 h = *(const float4*)(smem + byt);
        const float* wrow = (const float*)(smem + OFF_W3 + kg * W3SEC + (j * 4) * 36);
#pragma unroll
        for (int e = 0; e < 4; ++e) {
            float hv = (e == 0) ? h.x : (e == 1) ? h.y : (e == 2) ? h.z : h.w;
            const float* wr = wrow + e * 9;
#pragma unroll
            for (int o = 0; o < 9; ++o) p[o] += hv * wr[o];
        }
    }
#pragma unroll
    for (int o = 0; o < 9; ++o) {
        p[o] += __shfl_xor(p[o], 16);
        p[o] += __shfl_xor(p[o], 32);
    }

    // ---- tail (lanes kg==0, one row each): X = (M+I)@R, polar via scaled Newton ----
    {
        float* Rs = (float*)(smem + OFF_RS);
        float* Ms = (float*)(smem + OFF_MS);
        const float* b3s = (const float*)(smem + OFF_B3);
        if (kg == 0) {
            const int r = r3;
            const float m0 = p[0] + b3s[0] + 1.0f, m1 = p[1] + b3s[1],        m2 = p[2] + b3s[2];
            const float m3 = p[3] + b3s[3],        m4 = p[4] + b3s[4] + 1.0f, m5 = p[5] + b3s[5];
            const float m6 = p[6] + b3s[6],        m7 = p[7] + b3s[7],        m8 = p[8] + b3s[8] + 1.0f;
            const float r0 = Rs[r*12+0], r1 = Rs[r*12+1], r2 = Rs[r*12+2];
            const float r3v = Rs[r*12+3], r4 = Rs[r*12+4], r5 = Rs[r*12+5];
            const float r6 = Rs[r*12+6], r7 = Rs[r*12+7], r8 = Rs[r*12+8];

            float x0 = m0*r0 + m1*r3v + m2*r6;
            float x1 = m0*r1 + m1*r4  + m2*r7;
            float x2 = m0*r2 + m1*r5  + m2*r8;
            float x3 = m3*r0 + m4*r3v + m5*r6;
            float x4 = m3*r1 + m4*r4  + m5*r7;
            float x5 = m3*r2 + m4*r5  + m5*r8;
            float x6 = m6*r0 + m7*r3v + m8*r6;
            float x7 = m6*r1 + m7*r4  + m8*r7;
            float x8 = m6*r2 + m7*r5  + m8*r8;

#pragma unroll 1
            for (int it = 0; it < 16; ++it) {
                const float c0 = x4*x8 - x5*x7;
                const float c1 = x5*x6 - x3*x8;
                const float c2 = x3*x7 - x4*x6;
                const float c3 = x2*x7 - x1*x8;
                const float c4 = x0*x8 - x2*x6;
                const float c5 = x1*x6 - x0*x7;
                const float c6 = x1*x5 - x2*x4;
                const float c7 = x2*x3 - x0*x5;
                const float c8 = x0*x4 - x1*x3;
                const float det = x0*c0 + x1*c1 + x2*c2;
                const float ad  = fmaxf(fabsf(det), 1e-30f);
                const float mu  = 1.0f / cbrtf(ad);
                const float dsafe = copysignf(ad, det);
                const float s1 = 0.5f * mu;
                const float s2 = 0.5f / (mu * dsafe);
                x0 = s1*x0 + s2*c0;  x1 = s1*x1 + s2*c1;  x2 = s1*x2 + s2*c2;
                x3 = s1*x3 + s2*c3;  x4 = s1*x4 + s2*c4;  x5 = s1*x5 + s2*c5;
                x6 = s1*x6 + s2*c6;  x7 = s1*x7 + s2*c7;  x8 = s1*x8 + s2*c8;
            }
            Ms[r*12+0] = x0; Ms[r*12+1] = x1; Ms[r*12+2] = x2;
            Ms[r*12+3] = x3; Ms[r*12+4] = x4; Ms[r*12+5] = x5;
            Ms[r*12+6] = x6; Ms[r*12+7] = x7; Ms[r*12+8] = x8;
        }
    }
    __syncthreads();

    // ---- output: out (N*9) then logdet zeros (N) ----
    {
        float* Ms = (float*)(smem + OFF_MS);
        for (int t = tid; t < TM * 9; t += NT)
            out[(size_t)row0 * 9 + t] = Ms[(t / 9) * 12 + (t % 9)];
        for (int t = tid; t < TM; t += NT)
            out[(size_t)N_ROWS * 9 + row0 + t] = 0.0f;
    }
}

extern "C" void kernel_launch(void* const* d_in, const int* in_sizes, int n_in,
                              void* d_out, int out_size, void* d_ws, size_t ws_size,
                              hipStream_t stream) {
    const float* rot  = (const float*)d_in[0];
    const float* feat = (const float*)d_in[1];
    const float* W1   = (const float*)d_in[2];
    const float* b1   = (const float*)d_in[3];
    const float* W2   = (const float*)d_in[4];
    const float* b2   = (const float*)d_in[5];
    const float* W3   = (const float*)d_in[6];
    const float* b3   = (const float*)d_in[7];
    float* out = (float*)d_out;
    unsigned char* ws = (unsigned char*)d_ws;
    (void)in_sizes; (void)n_in; (void)out_size; (void)ws_size;

    hipLaunchKernelGGL(prep_weights, dim3(384), dim3(256), 0, stream, W1, W2, ws);
    hipLaunchKernelGGL(fused_main, dim3(NBLK), dim3(NT), 0, stream,
                       rot, feat, b1, b2, W3, b3, ws, out);
}